// Round 1
// baseline (163.247 us; speedup 1.0000x reference)
//
#include <hip/hip_runtime.h>
#include <hip/hip_bf16.h>

#define NEG_BIG -9000000000000000.0f
#define SLOPE 0.2f

constexpr int B = 8, N = 2048, FIN = 128, FOUT = 64;

// ---------------- K1: h = input @ W ; s1 = h@a1 ; s2 = h@a2 ----------------
// wave per row; lane o owns h[row][o]. 4 waves / block.
__global__ __launch_bounds__(256) void k1_h(
        const float* __restrict__ inp, const float* __restrict__ W,
        const float* __restrict__ a, float* __restrict__ h,
        float* __restrict__ s1, float* __restrict__ s2) {
    int wave = threadIdx.x >> 6;
    int lane = threadIdx.x & 63;
    int row  = blockIdx.x * 4 + wave;            // [0, B*N)
    const float* irow = inp + (size_t)row * FIN; // wave-uniform row, broadcast loads
    float acc = 0.f;
    #pragma unroll 16
    for (int k = 0; k < FIN; ++k) {
        acc = fmaf(irow[k], W[k * FOUT + lane], acc);  // W col read coalesced per wave
    }
    h[(size_t)row * FOUT + lane] = acc;
    float p1 = acc * a[lane];
    float p2 = acc * a[FOUT + lane];
    #pragma unroll
    for (int off = 32; off > 0; off >>= 1) {
        p1 += __shfl_down(p1, off);
        p2 += __shfl_down(p2, off);
    }
    if (lane == 0) { s1[row] = p1; s2[row] = p2; }
}

// ---------------- K2: masked row softmax -> attention ----------------------
// wave per (b,i) row; 32 logits per lane held in registers; two wave reductions.
__global__ __launch_bounds__(256) void k2_softmax(
        const float* __restrict__ s1, const float* __restrict__ s2,
        const int* __restrict__ adj, float* __restrict__ att) {
    int wave = threadIdx.x >> 6;
    int lane = threadIdx.x & 63;
    int gr = blockIdx.x * 4 + wave;              // [0, B*N)
    int b = gr >> 11;                            // / 2048
    int i = gr & (N - 1);
    float s1v = s1[gr];
    const float* s2b  = s2 + (size_t)b * N;
    const int*   arow = adj + (size_t)i * N;

    float v[32];
    float mx = -3.4e38f;
    #pragma unroll
    for (int t = 0; t < 32; ++t) {
        int j = t * 64 + lane;
        float e = s1v + s2b[j];
        e = (e > 0.f) ? e : SLOPE * e;           // leaky_relu(0.2)
        float m = (arow[j] > 0) ? e : NEG_BIG;   // mask AFTER lrelu (matches ref)
        v[t] = m;
        mx = fmaxf(mx, m);
    }
    #pragma unroll
    for (int off = 32; off > 0; off >>= 1) mx = fmaxf(mx, __shfl_xor(mx, off));
    float sum = 0.f;
    #pragma unroll
    for (int t = 0; t < 32; ++t) {
        v[t] = __expf(v[t] - mx);                // masked -> exp(-9e15) == 0 exactly
        sum += v[t];
    }
    #pragma unroll
    for (int off = 32; off > 0; off >>= 1) sum += __shfl_xor(sum, off);
    float r = 1.0f / sum;
    float* arow_out = att + (size_t)gr * N;
    #pragma unroll
    for (int t = 0; t < 32; ++t) arow_out[t * 64 + lane] = v[t] * r;  // coalesced
}

// ---------------- K3: out = relu(att @ h) (batched fp32 GEMM) ---------------
// M-tile 64, N = 64 (full), K-tile 32. 256 threads as 16x16; 4x4 per thread.
#define KT 32
__global__ __launch_bounds__(256) void k3_hprime(
        const float* __restrict__ att, const float* __restrict__ h,
        float* __restrict__ out) {
    __shared__ float aT[KT][68];   // att tile transposed: aT[k][m]; 68: 16B-aligned rows
    __shared__ float hs[KT][68];   // h tile: hs[k][o]
    int b  = blockIdx.y;
    int m0 = blockIdx.x * 64;
    const float* attb = att + ((size_t)b * N + m0) * N;
    const float* hb   = h + (size_t)b * N * FOUT;
    int tx = threadIdx.x & 15, ty = threadIdx.x >> 4;
    float acc[4][4] = {};
    for (int k0 = 0; k0 < N; k0 += KT) {
        #pragma unroll
        for (int r = 0; r < 8; ++r) {            // stage att^T: 64 rows x 32 k
            int idx = (int)threadIdx.x + 256 * r;
            int m = idx >> 5, k = idx & 31;
            aT[k][m] = attb[(size_t)m * N + k0 + k];
        }
        #pragma unroll
        for (int r = 0; r < 8; ++r) {            // stage h: 32 k x 64 o
            int idx = (int)threadIdx.x + 256 * r;
            int k = idx >> 6, o = idx & 63;
            hs[k][o] = hb[(size_t)(k0 + k) * FOUT + o];
        }
        __syncthreads();
        #pragma unroll
        for (int k = 0; k < KT; ++k) {
            float av[4], bv[4];
            #pragma unroll
            for (int i = 0; i < 4; ++i) av[i] = aT[k][ty * 4 + i];
            #pragma unroll
            for (int j = 0; j < 4; ++j) bv[j] = hs[k][tx * 4 + j];
            #pragma unroll
            for (int i = 0; i < 4; ++i)
                #pragma unroll
                for (int j = 0; j < 4; ++j)
                    acc[i][j] = fmaf(av[i], bv[j], acc[i][j]);
        }
        __syncthreads();
    }
    float* ob = out + ((size_t)b * N + m0) * FOUT;
    #pragma unroll
    for (int i = 0; i < 4; ++i) {
        int m = ty * 4 + i;
        #pragma unroll
        for (int j = 0; j < 4; ++j) {
            float vv = acc[i][j];
            ob[(size_t)m * FOUT + tx * 4 + j] = vv > 0.f ? vv : 0.f;
        }
    }
}

extern "C" void kernel_launch(void* const* d_in, const int* in_sizes, int n_in,
                              void* d_out, int out_size, void* d_ws, size_t ws_size,
                              hipStream_t stream) {
    const float* inp = (const float*)d_in[0];   // (8,2048,128) f32
    const int*   adj = (const int*)d_in[1];     // (2048,2048) i32
    const float* W   = (const float*)d_in[2];   // (128,64) f32
    const float* a   = (const float*)d_in[3];   // (128,1) f32

    float* out = (float*)d_out;                        // (8,2048,64)
    float* att = out + (size_t)B * N * FOUT;           // (8,2048,2048)

    float* h  = (float*)d_ws;                          // B*N*FOUT f32 = 4 MB
    float* s1 = h + (size_t)B * N * FOUT;              // B*N
    float* s2 = s1 + (size_t)B * N;                    // B*N

    k1_h<<<B * N / 4, 256, 0, stream>>>(inp, W, a, h, s1, s2);
    k2_softmax<<<B * N / 4, 256, 0, stream>>>(s1, s2, adj, att);
    dim3 g3(N / 64, B);
    k3_hprime<<<g3, 256, 0, stream>>>(att, h, out);
}

// Round 2
// 103.072 us; speedup vs baseline: 1.5838x; 1.5838x over previous
//
#include <hip/hip_runtime.h>
#include <hip/hip_bf16.h>

#define NEG_BIG -9000000000000000.0f

constexpr int B = 8, N = 2048, FIN = 128, FOUT = 64;

typedef __attribute__((ext_vector_type(8))) short short8;
typedef __attribute__((ext_vector_type(4))) float f32x4;

// round-to-nearest-even f32 -> bf16 bits (finite inputs only)
__device__ __forceinline__ unsigned short f2bf(float f) {
    unsigned int x = __float_as_uint(f);
    return (unsigned short)((x + 0x7fffu + ((x >> 16) & 1u)) >> 16);
}

// ---------------- K1: h = input @ W (bf16, row-major) ; s1 ; s2 ------------
__global__ __launch_bounds__(256) void k1_h(
        const float* __restrict__ inp, const float* __restrict__ W,
        const float* __restrict__ a, unsigned short* __restrict__ h,
        float* __restrict__ s1, float* __restrict__ s2) {
    int wave = threadIdx.x >> 6;
    int lane = threadIdx.x & 63;
    int row  = blockIdx.x * 4 + wave;            // [0, B*N)
    const float* irow = inp + (size_t)row * FIN; // wave-uniform -> s_load broadcast
    float acc = 0.f;
    #pragma unroll 16
    for (int k = 0; k < FIN; ++k)
        acc = fmaf(irow[k], W[k * FOUT + lane], acc);
    h[(size_t)row * FOUT + lane] = f2bf(acc);
    float p1 = acc * a[lane];
    float p2 = acc * a[FOUT + lane];
    #pragma unroll
    for (int off = 32; off > 0; off >>= 1) {
        p1 += __shfl_down(p1, off);
        p2 += __shfl_down(p2, off);
    }
    if (lane == 0) { s1[row] = p1; s2[row] = p2; }
}

// ---------------- K1b: hT[b][o][i] = h[b][i][o]  (bf16 transpose) ----------
__global__ __launch_bounds__(256) void k1b_t(
        const unsigned short* __restrict__ h, unsigned short* __restrict__ hT) {
    __shared__ unsigned short tile[64][72];      // stride 72 elems = 144 B (16-B aligned rows)
    int b = blockIdx.y, i0 = blockIdx.x * 64;
    int t = threadIdx.x;
    int r = t >> 2, cq = t & 3;
    const unsigned short* src = h + ((size_t)b * N + i0 + r) * FOUT + cq * 16;
    *(short8*)&tile[r][cq * 16]     = *(const short8*)src;
    *(short8*)&tile[r][cq * 16 + 8] = *(const short8*)(src + 8);
    __syncthreads();
    int o = t >> 2, iq = t & 3;
    union { short8 s8; unsigned short u[8]; } w0, w1;
    #pragma unroll
    for (int e = 0; e < 8; ++e) {
        w0.u[e] = tile[iq * 16 + e][o];
        w1.u[e] = tile[iq * 16 + 8 + e][o];
    }
    unsigned short* dst = hT + ((size_t)b * FOUT + o) * N + i0 + iq * 16;
    *(short8*)dst       = w0.s8;
    *(short8*)(dst + 8) = w1.s8;
}

// ------- K2: fused masked-softmax + att write + PV (MFMA) + relu(out) ------
// 512 thr / 8 waves per block; 32 rows per block; in-block 4-way K-split.
__global__ __launch_bounds__(512) void k2_fused(
        const float* __restrict__ s1g, const float* __restrict__ s2g,
        const int* __restrict__ adj, const unsigned short* __restrict__ hT,
        float* __restrict__ att, float* __restrict__ out) {
    __shared__ float s2l[N];                     // 8 KB
    __shared__ float s1l[32], mxl[32], rvl[32];
    __shared__ float red[3][32][65];             // ~25 KB partial-C reduce

    int b = blockIdx.y, m0 = blockIdx.x * 32;
    int t = threadIdx.x, w = t >> 6, lane = t & 63;

    for (int j = t; j < N; j += 512) s2l[j] = s2g[(size_t)b * N + j];
    if (t < 32) s1l[t] = s1g[(size_t)b * N + m0 + t];
    __syncthreads();

    // ---- pass A: per-row masked max & exp-sum (wave w -> rows 4w..4w+4) ----
    for (int rr = 0; rr < 4; ++rr) {
        int r = w * 4 + rr;
        float s1v = s1l[r];
        const int* arow = adj + (size_t)(m0 + r) * N;
        float v[32];
        float mx = -3.4e38f;
        #pragma unroll
        for (int tt = 0; tt < 32; ++tt) {
            int j = tt * 64 + lane;
            float e = s1v + s2l[j];
            e = (e > 0.f) ? e : 0.2f * e;
            float m = (arow[j] > 0) ? e : NEG_BIG;
            v[tt] = m;
            mx = fmaxf(mx, m);
        }
        #pragma unroll
        for (int off = 32; off > 0; off >>= 1) mx = fmaxf(mx, __shfl_xor(mx, off));
        float sum = 0.f;
        #pragma unroll
        for (int tt = 0; tt < 32; ++tt) sum += __expf(v[tt] - mx);
        #pragma unroll
        for (int off = 32; off > 0; off >>= 1) sum += __shfl_xor(sum, off);
        if (lane == 0) { mxl[r] = mx; rvl[r] = 1.0f / sum; }
    }
    __syncthreads();

    // ---- pass B: att write + MFMA PV; wave w: row-stripe s, K-chunk kc ----
    int s  = w & 1;            // 16-row stripe
    int kc = w >> 1;           // K chunk of 512
    int r  = lane & 15;        // A row / B col within 16
    int g  = lane >> 4;        // k-octet group
    int rowg = m0 + 16 * s + r;
    float mxv = mxl[16 * s + r], rv = rvl[16 * s + r], s1v = s1l[16 * s + r];
    const int* arow = adj + (size_t)rowg * N;
    float* attrow = att + ((size_t)b * N + rowg) * N;

    f32x4 acc[4];
    #pragma unroll
    for (int nf = 0; nf < 4; ++nf)
        #pragma unroll
        for (int q = 0; q < 4; ++q) acc[nf][q] = 0.f;

    for (int step = 0; step < 16; ++step) {
        int jb = kc * 512 + step * 32 + g * 8;
        int4 a0 = *(const int4*)&arow[jb];
        int4 a1 = *(const int4*)&arow[jb + 4];
        float4 sA = *(const float4*)&s2l[jb];
        float4 sB = *(const float4*)&s2l[jb + 4];
        int   ai[8] = {a0.x, a0.y, a0.z, a0.w, a1.x, a1.y, a1.z, a1.w};
        float sj[8] = {sA.x, sA.y, sA.z, sA.w, sB.x, sB.y, sB.z, sB.w};
        float p[8];
        #pragma unroll
        for (int e = 0; e < 8; ++e) {
            float sm = s1v + sj[e];
            float lr = (sm > 0.f) ? sm : 0.2f * sm;
            float mk = (ai[e] > 0) ? lr : NEG_BIG;
            p[e] = __expf(mk - mxv) * rv;        // masked -> exactly 0; empty row -> rv
        }
        float4 o0 = {p[0], p[1], p[2], p[3]};
        float4 o1 = {p[4], p[5], p[6], p[7]};
        *(float4*)&attrow[jb]     = o0;
        *(float4*)&attrow[jb + 4] = o1;

        union { short8 s8; unsigned short u[8]; } pk;
        #pragma unroll
        for (int e = 0; e < 8; ++e) pk.u[e] = f2bf(p[e]);

        const unsigned short* hb = hT + (size_t)b * FOUT * N + jb;
        #pragma unroll
        for (int nf = 0; nf < 4; ++nf) {
            short8 Bf = *(const short8*)&hb[(size_t)(nf * 16 + r) * N];
            acc[nf] = __builtin_amdgcn_mfma_f32_16x16x32_bf16(pk.s8, Bf, acc[nf], 0, 0, 0);
        }
    }

    __syncthreads();
    // ---- combine K-chunk partials through LDS; waves kc==0 write out ------
    if (kc > 0) {
        #pragma unroll
        for (int nf = 0; nf < 4; ++nf)
            #pragma unroll
            for (int q = 0; q < 4; ++q)
                red[kc - 1][16 * s + 4 * g + q][nf * 16 + r] = acc[nf][q];
    }
    __syncthreads();
    if (kc == 0) {
        #pragma unroll
        for (int nf = 0; nf < 4; ++nf) {
            #pragma unroll
            for (int q = 0; q < 4; ++q) {
                int lr = 16 * s + 4 * g + q;     // local out row (C/D: row=(lane>>4)*4+q)
                int lc = nf * 16 + r;            // out col      (C/D: col=lane&15)
                float vv = acc[nf][q] + red[0][lr][lc] + red[1][lr][lc] + red[2][lr][lc];
                out[((size_t)b * N + m0 + lr) * FOUT + lc] = vv > 0.f ? vv : 0.f;
            }
        }
    }
}

extern "C" void kernel_launch(void* const* d_in, const int* in_sizes, int n_in,
                              void* d_out, int out_size, void* d_ws, size_t ws_size,
                              hipStream_t stream) {
    const float* inp = (const float*)d_in[0];   // (8,2048,128) f32
    const int*   adj = (const int*)d_in[1];     // (2048,2048) i32
    const float* W   = (const float*)d_in[2];   // (128,64) f32
    const float* a   = (const float*)d_in[3];   // (128,1) f32

    float* out = (float*)d_out;                        // (8,2048,64)
    float* att = out + (size_t)B * N * FOUT;           // (8,2048,2048)

    // ws: h bf16 (2 MB) | hT bf16 (2 MB) | s1 (64 KB) | s2 (64 KB)
    unsigned short* h  = (unsigned short*)d_ws;
    unsigned short* hT = h + (size_t)B * N * FOUT;
    float* s1 = (float*)(hT + (size_t)B * N * FOUT);
    float* s2 = s1 + (size_t)B * N;

    k1_h<<<B * N / 4, 256, 0, stream>>>(inp, W, a, h, s1, s2);
    dim3 gt(N / 64, B);
    k1b_t<<<gt, 256, 0, stream>>>(h, hT);
    dim3 g2(N / 32, B);
    k2_fused<<<g2, 512, 0, stream>>>(s1, s2, adj, hT, att, out);
}

// Round 3
// 99.755 us; speedup vs baseline: 1.6365x; 1.0332x over previous
//
#include <hip/hip_runtime.h>
#include <hip/hip_bf16.h>

#define NEG_BIG -9000000000000000.0f

constexpr int B = 8, N = 2048, FIN = 128, FOUT = 64;

typedef __attribute__((ext_vector_type(8))) short short8;
typedef __attribute__((ext_vector_type(4))) float f32x4;

// round-to-nearest-even f32 -> bf16 bits (finite inputs only)
__device__ __forceinline__ unsigned short f2bf(float f) {
    unsigned int x = __float_as_uint(f);
    return (unsigned short)((x + 0x7fffu + ((x >> 16) & 1u)) >> 16);
}

// ---------------- K1: h = input @ W (bf16, row-major) ; s1 ; s2 ------------
__global__ __launch_bounds__(256) void k1_h(
        const float* __restrict__ inp, const float* __restrict__ W,
        const float* __restrict__ a, unsigned short* __restrict__ h,
        float* __restrict__ s1, float* __restrict__ s2) {
    int wave = threadIdx.x >> 6;
    int lane = threadIdx.x & 63;
    int row  = blockIdx.x * 4 + wave;            // [0, B*N)
    const float* irow = inp + (size_t)row * FIN;
    float acc = 0.f;
    #pragma unroll 16
    for (int k = 0; k < FIN; ++k)
        acc = fmaf(irow[k], W[k * FOUT + lane], acc);
    h[(size_t)row * FOUT + lane] = f2bf(acc);
    float p1 = acc * a[lane];
    float p2 = acc * a[FOUT + lane];
    #pragma unroll
    for (int off = 32; off > 0; off >>= 1) {
        p1 += __shfl_down(p1, off);
        p2 += __shfl_down(p2, off);
    }
    if (lane == 0) { s1[row] = p1; s2[row] = p2; }
}

// ---------------- K1b: hT[b][o][i] = h[b][i][o]  (bf16 transpose) ----------
__global__ __launch_bounds__(256) void k1b_t(
        const unsigned short* __restrict__ h, unsigned short* __restrict__ hT) {
    __shared__ unsigned short tile[64][72];
    int b = blockIdx.y, i0 = blockIdx.x * 64;
    int t = threadIdx.x;
    int r = t >> 2, cq = t & 3;
    const unsigned short* src = h + ((size_t)b * N + i0 + r) * FOUT + cq * 16;
    *(short8*)&tile[r][cq * 16]     = *(const short8*)src;
    *(short8*)&tile[r][cq * 16 + 8] = *(const short8*)(src + 8);
    __syncthreads();
    int o = t >> 2, iq = t & 3;
    union { short8 s8; unsigned short u[8]; } w0, w1;
    #pragma unroll
    for (int e = 0; e < 8; ++e) {
        w0.u[e] = tile[iq * 16 + e][o];
        w1.u[e] = tile[iq * 16 + 8 + e][o];
    }
    unsigned short* dst = hT + ((size_t)b * FOUT + o) * N + i0 + iq * 16;
    *(short8*)dst       = w0.s8;
    *(short8*)(dst + 8) = w1.s8;
}

// ------- K2: fused masked-softmax + att write + PV (MFMA) + relu(out) ------
// 512 thr / 8 waves; 32 rows per block (2 groups of 16) x 4-way K-split.
// Wave (s = w&1 row-group, kc = w>>1 K-chunk). Lane (g = lane>>4, r = lane&15):
// owns row s*16+r, k in {kc*512 + st*32 + g*8 .. +7}, st = 0..15.
// adj is read ONCE (pass A) and kept as a 128-bit per-lane register bitmask.
__global__ __launch_bounds__(512, 4) void k2_fused(
        const float* __restrict__ s1g, const float* __restrict__ s2g,
        const int* __restrict__ adj, const unsigned short* __restrict__ hT,
        float* __restrict__ att, float* __restrict__ out) {
    __shared__ float s2l[N];                     // 8 KB
    __shared__ float s1l[32];
    __shared__ float pm[4][32], ps[4][32];       // per-K-chunk (max, expsum)
    __shared__ float red[3][32][68];             // ~26 KB partial-C reduce

    int b = blockIdx.y, m0 = blockIdx.x * 32;
    int t = threadIdx.x, w = t >> 6, lane = t & 63;
    int s = w & 1, kc = w >> 1;
    int r = lane & 15, g = lane >> 4;

    for (int j = t; j < N; j += 512) s2l[j] = s2g[(size_t)b * N + j];
    if (t < 32) s1l[t] = s1g[(size_t)b * N + m0 + t];
    __syncthreads();

    int lrow = s * 16 + r;
    int rowg = m0 + lrow;
    float s1v = s1l[lrow];
    const int* arow = adj + (size_t)rowg * N;

    // ---- pass A: online masked max/expsum over this lane's k-slice --------
    float m_run = NEG_BIG, s_run = 0.f;
    unsigned bm0 = 0, bm1 = 0, bm2 = 0, bm3 = 0;
    #pragma unroll
    for (int st = 0; st < 16; ++st) {
        int jb = kc * 512 + st * 32 + g * 8;
        int4 a0 = *(const int4*)&arow[jb];
        int4 a1 = *(const int4*)&arow[jb + 4];
        float4 sA = *(const float4*)&s2l[jb];
        float4 sB = *(const float4*)&s2l[jb + 4];
        int   ai[8] = {a0.x, a0.y, a0.z, a0.w, a1.x, a1.y, a1.z, a1.w};
        float sj[8] = {sA.x, sA.y, sA.z, sA.w, sB.x, sB.y, sB.z, sB.w};
        unsigned bits = 0u;
        float em[8];
        #pragma unroll
        for (int e = 0; e < 8; ++e) {
            float x = s1v + sj[e];
            x = fmaxf(x, 0.2f * x);              // leaky_relu(0.2)
            bool bt = ai[e] > 0;
            em[e] = bt ? x : NEG_BIG;
            bits |= (bt ? 1u : 0u) << e;
        }
        float lm = fmaxf(fmaxf(fmaxf(em[0], em[1]), fmaxf(em[2], em[3])),
                         fmaxf(fmaxf(em[4], em[5]), fmaxf(em[6], em[7])));
        float mn = fmaxf(m_run, lm);
        float acc8 = 0.f;
        #pragma unroll
        for (int e = 0; e < 8; ++e) acc8 += __expf(em[e] - mn);
        s_run = s_run * __expf(m_run - mn) + acc8;   // m_run==mn -> *1
        m_run = mn;
        if      (st < 4)  bm0 |= bits << (st * 8);
        else if (st < 8)  bm1 |= bits << ((st - 4) * 8);
        else if (st < 12) bm2 |= bits << ((st - 8) * 8);
        else              bm3 |= bits << ((st - 12) * 8);
    }
    // reduce (m,s) across the 4 lanes sharing row r (xor 16, 32)
    #pragma unroll
    for (int off = 16; off <= 32; off <<= 1) {
        float mo = __shfl_xor(m_run, off);
        float so = __shfl_xor(s_run, off);
        float mn = fmaxf(m_run, mo);
        s_run = s_run * __expf(m_run - mn) + so * __expf(mo - mn);
        m_run = mn;
    }
    if (lane < 16) { pm[kc][lrow] = m_run; ps[kc][lrow] = s_run; }
    __syncthreads();
    // combine the 4 K-chunk partials (every thread, for its row)
    float M0 = pm[0][lrow], M1 = pm[1][lrow], M2 = pm[2][lrow], M3 = pm[3][lrow];
    float mx = fmaxf(fmaxf(M0, M1), fmaxf(M2, M3));
    float sum = ps[0][lrow] * __expf(M0 - mx) + ps[1][lrow] * __expf(M1 - mx)
              + ps[2][lrow] * __expf(M2 - mx) + ps[3][lrow] * __expf(M3 - mx);
    float rv = 1.0f / sum;

    // ---- pass B: recompute p from s2l + bitmask; write att; MFMA PV -------
    float* attrow = att + ((size_t)b * N + rowg) * N;
    const unsigned short* hbase = hT + (size_t)b * FOUT * N;
    f32x4 acc[4];
    #pragma unroll
    for (int nf = 0; nf < 4; ++nf)
        #pragma unroll
        for (int q = 0; q < 4; ++q) acc[nf][q] = 0.f;

    for (int q4 = 0; q4 < 4; ++q4) {
        unsigned bmq = (q4 == 0) ? bm0 : (q4 == 1) ? bm1 : (q4 == 2) ? bm2 : bm3;
        #pragma unroll
        for (int si = 0; si < 4; ++si) {
            int st = q4 * 4 + si;
            int jb = kc * 512 + st * 32 + g * 8;
            float4 sA = *(const float4*)&s2l[jb];
            float4 sB = *(const float4*)&s2l[jb + 4];
            float sj[8] = {sA.x, sA.y, sA.z, sA.w, sB.x, sB.y, sB.z, sB.w};
            unsigned bits = bmq >> (si * 8);
            float p[8];
            #pragma unroll
            for (int e = 0; e < 8; ++e) {
                float x = s1v + sj[e];
                x = fmaxf(x, 0.2f * x);
                float pe = __expf(x - mx) * rv;
                p[e] = ((bits >> e) & 1u) ? pe : 0.f;   // masked -> exact 0
            }
            float4 o0 = {p[0], p[1], p[2], p[3]};
            float4 o1 = {p[4], p[5], p[6], p[7]};
            *(float4*)&attrow[jb]     = o0;              // 32B/lane contiguous
            *(float4*)&attrow[jb + 4] = o1;
            union { short8 s8; unsigned short u[8]; } pk;
            #pragma unroll
            for (int e = 0; e < 8; ++e) pk.u[e] = f2bf(p[e]);
            #pragma unroll
            for (int nf = 0; nf < 4; ++nf) {
                short8 Bf = *(const short8*)&hbase[(size_t)(nf * 16 + r) * N + jb];
                acc[nf] = __builtin_amdgcn_mfma_f32_16x16x32_bf16(pk.s8, Bf, acc[nf], 0, 0, 0);
            }
        }
    }

    __syncthreads();
    if (kc > 0) {
        #pragma unroll
        for (int nf = 0; nf < 4; ++nf)
            #pragma unroll
            for (int q = 0; q < 4; ++q)
                red[kc - 1][s * 16 + 4 * g + q][nf * 16 + r] = acc[nf][q];
    }
    __syncthreads();
    if (kc == 0) {
        #pragma unroll
        for (int nf = 0; nf < 4; ++nf) {
            #pragma unroll
            for (int q = 0; q < 4; ++q) {
                int lr = s * 16 + 4 * g + q;     // C/D: row=(lane>>4)*4+reg
                int lc = nf * 16 + r;            // C/D: col=lane&15
                float vv = acc[nf][q] + red[0][lr][lc] + red[1][lr][lc] + red[2][lr][lc];
                out[((size_t)b * N + m0 + lr) * FOUT + lc] = vv > 0.f ? vv : 0.f;
            }
        }
    }
}

extern "C" void kernel_launch(void* const* d_in, const int* in_sizes, int n_in,
                              void* d_out, int out_size, void* d_ws, size_t ws_size,
                              hipStream_t stream) {
    const float* inp = (const float*)d_in[0];   // (8,2048,128) f32
    const int*   adj = (const int*)d_in[1];     // (2048,2048) i32
    const float* W   = (const float*)d_in[2];   // (128,64) f32
    const float* a   = (const float*)d_in[3];   // (128,1) f32

    float* out = (float*)d_out;                        // (8,2048,64)
    float* att = out + (size_t)B * N * FOUT;           // (8,2048,2048)

    unsigned short* h  = (unsigned short*)d_ws;        // 2 MB bf16
    unsigned short* hT = h + (size_t)B * N * FOUT;     // 2 MB bf16
    float* s1 = (float*)(hT + (size_t)B * N * FOUT);
    float* s2 = s1 + (size_t)B * N;

    k1_h<<<B * N / 4, 256, 0, stream>>>(inp, W, a, h, s1, s2);
    dim3 gt(N / 64, B);
    k1b_t<<<gt, 256, 0, stream>>>(h, hT);
    dim3 g2(N / 32, B);
    k2_fused<<<g2, 512, 0, stream>>>(s1, s2, adj, hT, att, out);
}